// Round 17
// baseline (667.599 us; speedup 1.0000x reference)
//
#include <hip/hip_runtime.h>
#include <hip/hip_bf16.h>

#define TT 64
#define BB 4096
#define HH 256
#define BMb 16             // batches per block
#define NBLK (BB / BMb)    // 256 blocks -> 1 block/CU, 8 waves (2/SIMD)
#define TC 4               // timesteps per weight pass (chunk)
#define NCH (TT / TC)      // 16 chunks

typedef short bf16x8_t __attribute__((ext_vector_type(8)));
typedef float f32x4_t  __attribute__((ext_vector_type(4)));

// d_ws layout (byte offsets)
#define WS_WA_B   0u          // split bf16 weights: 2 layers*3 parts*8kt*16nt*64lane*8j shorts = 768 KB
#define WS_EMB_B  786432u     // emb f32
#define WS_REC_B  1048576u    // rec f32 [T][B][4], 4 MB

__device__ __forceinline__ float clip01f(float v) {
    return fminf(fmaxf(v, 0.0f), 1.0f);
}

__global__ __launch_bounds__(64) void setup_emb_kernel(float* __restrict__ emb) {
    int i = threadIdx.x;
    const double sigma = 64.0 / 10.0;
    const double c = 32.0;
    double d = ((double)i - c) / sigma;
    double e = exp(-0.5 * (d * d));
    double d0 = (0.0 - c) / sigma;
    double emin = exp(-0.5 * (d0 * d0));
    emb[i] = (float)((e - emin) / (1.0 - emin));
}

// Exact 3-way split w = hi + mid + lo into bf16 parts (residuals exact).
// Pre-swizzled to A-fragment order for mfma_f32_16x16x32_bf16:
// A[m=lane&15][k=(lane>>4)*8+j], flat = ((((layer*3+part)*8+kt)*16+ntile)*64+lane)*8+j
__global__ __launch_bounds__(256) void split_weights_kernel(
    const float* __restrict__ W_h, const float* __restrict__ W_h2,
    unsigned short* __restrict__ WA)
{
    int flat = blockIdx.x * 256 + threadIdx.x;     // < 393216
    int j     = flat & 7;
    int lane  = (flat >> 3) & 63;
    int ntile = (flat >> 9) & 15;
    int kt    = (flat >> 13) & 7;
    int rest  = flat >> 16;                        // 0..5
    int part  = rest % 3;
    int layer = rest / 3;
    int k = kt * 32 + (lane >> 4) * 8 + j;
    int n = ntile * 16 + (lane & 15);
    const float* W = layer ? W_h2 : W_h;           // row-major [n][k] = W[n*256+k]
    float w = W[n * HH + k];
    __hip_bfloat16 h = __float2bfloat16(w);
    float r1 = w - __bfloat162float(h);
    __hip_bfloat16 m = __float2bfloat16(r1);
    float r2 = r1 - __bfloat162float(m);
    __hip_bfloat16 l = __float2bfloat16(r2);
    __hip_bfloat16 v = (part == 0) ? h : ((part == 1) ? m : l);
    WA[flat] = *reinterpret_cast<unsigned short*>(&v);
}

union U16x8 { uint4 u; bf16x8_t v; };

// ---- TC=4 @ 512thr + surgery v2: the last held-register item (s2w, 16 regs
// across BAR2) replaced by a 2KB ballot table S2M (same trick epi3 already
// uses for M3L): epi2 ballots spike bits; after BAR2 each thread rebuilds its
// frag words from its own lane bit -> pure data movement, bit-identical.
// R16 evidence: FETCH 363MB ~ all-weights-miss-every-pass; R8 proves weights
// are L2-resident when scratch is zero -> killing the last spill should
// restore FETCH ~11MB and remove ~900cy HBM stragglers inside vmcnt(6) steps.
// xs staging dropped (12KB LDS freed for S2M); phase A reads x from global
// (identical addresses/values). Per-D accumulation order unchanged (kt asc,
// parts 0,1,2, one MFMA per part per kt) -> canary absmax 0.002365112.

#define AS1 __attribute__((address_space(1)))
#define AS3 __attribute__((address_space(3)))
__device__ __forceinline__ void gl16(const void* g, void* l) {
    __builtin_amdgcn_global_load_lds((AS1 const void*)g, (AS3 void*)l, 16, 0, 0);
}

// Issue the 6 loads of kt-group ktn of weight base Wc into ring slot sl.
// Wc is pre-offset by (2w)*64+lane in uint4 units (byte = *16). Strides (B):
// part 131072, kt 16384, tile 1024. Chunk order in slot: (part*2 + tile).
#define ISSUE6(Wc, ktn, sl) do {                                               \
    const char* gb_ = (const char*)(Wc) + (ktn) * 16384;                       \
    char* lb_ = myring + (sl) * 6144;                                          \
    gl16(gb_,          lb_);                                                   \
    gl16(gb_ + 1024,   lb_ + 1024);                                            \
    gl16(gb_ + 131072, lb_ + 2048);                                            \
    gl16(gb_ + 132096, lb_ + 3072);                                            \
    gl16(gb_ + 262144, lb_ + 4096);                                            \
    gl16(gb_ + 263168, lb_ + 5120);                                            \
} while (0)

// 8 MFMAs of one weight part: per tt, read its B-frag locally, 2 MFMAs, release.
#define MFMA8T(wa_, wb_, ktb) do {                                             \
    _Pragma("unroll")                                                          \
    for (int tt_ = 0; tt_ < TC; ++tt_) {                                       \
        U16x8 br_; br_.u = BfL[tt_ * 512 + (ktb) * 64];                        \
        D0[tt_] = __builtin_amdgcn_mfma_f32_16x16x32_bf16(wa_.v, br_.v, D0[tt_], 0, 0, 0); \
        D1[tt_] = __builtin_amdgcn_mfma_f32_16x16x32_bf16(wb_.v, br_.v, D1[tt_], 0, 0, 0); \
    }                                                                          \
} while (0)

// One kt step: head vmcnt(6) [kt landed; newer 6 in flight]; 3 part-blocks
// with NO asm except part-2's lgkmcnt(0)+SB right before ISSUE6 (WAR proof).
#define STEPT(sl, ktb, Wi, kti) do {                                           \
    asm volatile("s_waitcnt vmcnt(6)" ::: "memory");                           \
    __builtin_amdgcn_sched_barrier(0);                                         \
    {                                                                          \
        U16x8 wa_, wb_;                                                        \
        wa_.u = ringRd[(sl) * 384 + 0];                                        \
        wb_.u = ringRd[(sl) * 384 + 64];                                       \
        MFMA8T(wa_, wb_, ktb);                                                 \
    }                                                                          \
    {                                                                          \
        U16x8 wa_, wb_;                                                        \
        wa_.u = ringRd[(sl) * 384 + 128];                                      \
        wb_.u = ringRd[(sl) * 384 + 192];                                      \
        MFMA8T(wa_, wb_, ktb);                                                 \
    }                                                                          \
    {                                                                          \
        U16x8 wa_, wb_;                                                        \
        wa_.u = ringRd[(sl) * 384 + 256];                                      \
        wb_.u = ringRd[(sl) * 384 + 320];                                      \
        asm volatile("s_waitcnt lgkmcnt(0)" ::: "memory");                     \
        __builtin_amdgcn_sched_barrier(0);                                     \
        ISSUE6(Wi, kti, sl);                                                   \
        MFMA8T(wa_, wb_, ktb);                                                 \
    }                                                                          \
} while (0)

// kt = 0..7 ascending; entry: slot0=kt0, slot1=kt1 landed (barrier vmcnt drain).
// Steps 0..5 refill kt+2; steps 6,7 preload the NEXT pass's kt0,kt1 (Wn).
#define GPHASE(Wc, Wn) do {                                                    \
    STEPT(0, 0, Wc, 2);                                                        \
    STEPT(1, 1, Wc, 3);                                                        \
    STEPT(0, 2, Wc, 4);                                                        \
    STEPT(1, 3, Wc, 5);                                                        \
    STEPT(0, 4, Wc, 6);                                                        \
    STEPT(1, 5, Wc, 7);                                                        \
    STEPT(0, 6, Wn, 0);                                                        \
    STEPT(1, 7, Wn, 1);                                                        \
} while (0)

// p-dot for one timestep (no recurrence -> parallel across waves). Ascending-k
// chain p = p + (bit ? wv : 0), identical text/order to the verified walker ->
// bit-identical p. One lane computes one (batch, channel) pair.
__device__ __forceinline__ void compute_p(
    const float* __restrict__ WoutS, const unsigned long long (*__restrict__ M3Lt)[4],
    int wb, int ooc, float* __restrict__ pout, int lane)
{
    if (lane < 32) {
        float p = 0.f;
        for (int k = 0; k < HH; ++k) {
            int ww = k >> 4, gg = (k >> 2) & 3, reg = k & 3;
            unsigned long long word = M3Lt[ww][reg];
            unsigned w32 = (gg < 2) ? (unsigned)word : (unsigned)(word >> 32);
            int sh = ((gg & 1) << 4) | wb;
            unsigned bit = (w32 >> sh) & 1u;
            float wv = WoutS[ooc * HH + k];
            p = p + (bit ? wv : 0.f);           // skip-zero == exact chain
        }
        pout[lane] = p;
    }
}

// Full serial walker — used only for the final chunk. Identical chains.
__device__ __forceinline__ void li_walker_bits(
    const float* __restrict__ WoutS, const unsigned long long (*__restrict__ M3Lt)[4],
    int wb, int ooc, float bto, float bo, float& m3s,
    float* __restrict__ rec, int t, int b0, int lane)
{
    if (lane < 32) {
        float p = 0.f;
        for (int k = 0; k < HH; ++k) {
            int ww = k >> 4, gg = (k >> 2) & 3, reg = k & 3;
            unsigned long long word = M3Lt[ww][reg];
            unsigned w32 = (gg < 2) ? (unsigned)word : (unsigned)(word >> 32);
            int sh = ((gg & 1) << 4) | wb;
            unsigned bit = (w32 >> sh) & 1u;
            float wv = WoutS[ooc * HH + k];
            p = p + (bit ? wv : 0.f);
        }
        float mm3 = fmaf(bto, m3s, p);
        mm3 = mm3 + bo;
        m3s = mm3;
        float spk = ((m3s - 1.0f) > 0.f) ? 1.f : 0.f;
        float om3 = __shfl_xor(m3s, 16, 64);
        float osp = __shfl_xor(spk, 16, 64);
        if (lane < 16) {
            *(float4*)(rec + ((size_t)t * BB + b0 + wb) * 4) =
                make_float4(spk, osp, m3s, om3);
        }
    }
}

__global__ __launch_bounds__(512) void snn_main_kernel(
    const float* __restrict__ x,
    const float* __restrict__ W_in, const float* __restrict__ b_in,
    const float* __restrict__ beta_in, const float* __restrict__ thr_in,
    const float* __restrict__ b_h, const float* __restrict__ beta_h, const float* __restrict__ thr_h,
    const float* __restrict__ b_h2, const float* __restrict__ beta_h2, const float* __restrict__ thr_h2,
    const float* __restrict__ W_out, const float* __restrict__ b_out, const float* __restrict__ beta_out,
    const unsigned short* __restrict__ WA, const float* __restrict__ emb,
    float* __restrict__ rec)
{
#pragma clang fp contract(off)   // all contraction EXPLICIT via fmaf
    const int tid = threadIdx.x;
    const int w = tid >> 6;       // wave 0..7: owns n-tiles 2w, 2w+1
    const int lane = tid & 63;
    const int b = lane & 15;      // batch column (D col = lane&15)
    const int g = lane >> 4;      // row group   (D row = g*4+reg)
    const int b0 = blockIdx.x * BMb;

    // B-frag buffer: s1 for GEMM2; rebuilt in place with s2 (from S2M ballots)
    // after BAR2; GEMM3 reads after BAR3. 32 KB.
    __shared__ __align__(16) unsigned short frag[TC][8 * 64 * 8];
    __shared__ unsigned long long M3L[TC][16][4];           // s3 ballots (2 KB)
    __shared__ unsigned long long S2M[TC][16][4];           // s2 ballots (2 KB)
    __shared__ float pbuf[TC][32];                          // li_out dots (512 B)
    __shared__ __align__(16) float WoutS[2 * HH];
    __shared__ float4 PL1a[HH];   // {wi0, wi1, wi2, b_in}
    __shared__ float2 PL1b[HH];   // {bt1c, th1}
    __shared__ float4 PL2[HH];    // {b_h,  bt2c, th2, -}
    __shared__ float4 PL3[HH];    // {b_h2, bt3c, th3, -}
    __shared__ float  embS[TT];
    // Wave-local weight ring: 8 waves x 2 slots x 6KB = 96 KB. Total ~149 KB
    // (xs staging dropped; phase A reads x from global).
    __shared__ __align__(16) char ring[8 * 2 * 6144];

    char* myring = ring + w * 12288;                        // wave-uniform dest base
    const uint4* ringRd = (const uint4*)(ring + w * 12288 + lane * 16);
    const uint4* BfL = (const uint4*)frag + lane;           // B-frag read base

    WoutS[tid] = W_out[tid];      // 512 threads = 512 elems
    if (tid < HH) {
        int n = tid;
        PL1a[n] = make_float4(W_in[n * 3], W_in[n * 3 + 1], W_in[n * 3 + 2], b_in[n]);
        PL1b[n] = make_float2(clip01f(beta_in[n]), thr_in[n]);
        PL2[n]  = make_float4(b_h[n],  clip01f(beta_h[n]),  thr_h[n],  0.f);
        PL3[n]  = make_float4(b_h2[n], clip01f(beta_h2[n]), thr_h2[n], 0.f);
    }
    if (tid < TT) embS[tid] = emb[tid];

    // this thread's 8 neurons: n = (2w+u)*16 + g*4 + r, u in {0,1}
    const int nb0 = w * 32 + g * 4;

    float m1[2][4], m2[2][4], m4[2][4];
#pragma unroll
    for (int u = 0; u < 2; ++u)
#pragma unroll
        for (int r = 0; r < 4; ++r) { m1[u][r] = 0.f; m2[u][r] = 0.f; m4[u][r] = 0.f; }

    // spike -> B-frag LDS address for tile nt=2w+u (one b64 per thread per tile):
    // k=n: kt2 = nt>>1 = w, q = (nt&1)*2 + (g>>1), dst_lane = q*16+b, j0 = (g&1)*4
    const int sb0 = ((w * 64 + ((g >> 1) * 16 + b)) * 8 + (g & 1) * 4);

    // li_out walker state (lanes 0..31): wb = batch, ooc = channel
    const int wb = lane & 15;
    const int ooc = (lane >> 4) & 1;
    float bto = clip01f(beta_out[ooc]);
    float bo = b_out[ooc];
    float m3s = 0.f;

    // A-fragment bases (uint4 units); layer stride 24576 u4.
    const uint4* W2 = (const uint4*)WA + (size_t)(2 * w) * 64 + lane;   // layer2
    const uint4* W3 = W2 + 24576;                                       // layer3

    ISSUE6(W2, 0, 0);             // chunk-0 layer-2 kt0 in flight before the loop
    ISSUE6(W2, 1, 1);             // chunk-0 layer-2 kt1 (depth-2 invariant)

    __syncthreads();              // LDS init visible; also drains the preloads

#pragma unroll 1
    for (int c = 0; c < NCH; ++c) {
        const int t0 = c * TC;

        // ---- phase A: layer 1 for TC timesteps (m1 recurrence sequential);
        //      x read directly from global (identical values to old staging);
        //      spikes -> s1 B-frags ----
#pragma unroll
        for (int tt = 0; tt < TC; ++tt) {
            const int t = t0 + tt;
            float et = embS[t];
            const float* xp = x + ((size_t)t * BB + b0 + b) * 3;
            float xe0 = xp[0] * et;
            float xe1 = xp[1] * et;
            float xe2 = xp[2] * et;
            unsigned sp[2][4];
#pragma unroll
            for (int u = 0; u < 2; ++u)
#pragma unroll
            for (int r = 0; r < 4; ++r) {
                int n = nb0 + u * 16 + r;
                float4 pa = PL1a[n];
                float2 pb = PL1b[n];
                float a1 = xe0 * pa.x;
                a1 = fmaf(xe1, pa.y, a1);
                a1 = fmaf(xe2, pa.z, a1);
                float cur = a1 + pa.w;
                float rf = ((m1[u][r] - pb.y) > 0.f) ? 1.f : 0.f;  // reset from PREVIOUS mem
                float mm = fmaf(pb.x, m1[u][r], cur);              // contracted: beta*m + cur
                mm = fmaf(-rf, pb.y, mm);                          // contracted: - reset*thr
                m1[u][r] = mm;
                sp[u][r] = ((mm - pb.y) > 0.f) ? 0x3F80u : 0u;     // bf16 1.0 / 0.0
            }
            *(uint2*)(&frag[tt][sb0])       = make_uint2(sp[0][0] | (sp[0][1] << 16), sp[0][2] | (sp[0][3] << 16));
            *(uint2*)(&frag[tt][sb0 + 256]) = make_uint2(sp[1][0] | (sp[1][1] << 16), sp[1][2] | (sp[1][3] << 16));
        }
        __syncthreads();   // BAR1: s1 frags visible; ring kt0,kt1 landed

        // ---- waves 0..3: previous chunk's li_out dots (wave w -> tt=w),
        //      hidden under GEMM2. M3L(prev) rewritten only in epi3. ----
        if (w < TC && c > 0)
            compute_p(WoutS, M3L[w], wb, ooc, pbuf[w], lane);

        // ---- GEMM2: one weight pass (layer 2) feeds all TC timesteps ----
        f32x4_t D0[TC], D1[TC];
#pragma unroll
        for (int tt = 0; tt < TC; ++tt) {
            D0[tt] = (f32x4_t){0.f, 0.f, 0.f, 0.f};
            D1[tt] = (f32x4_t){0.f, 0.f, 0.f, 0.f};
        }
        GPHASE(W2, W3);            // steps 6,7 preload layer-3 kt0,kt1

        // epi2: LIF2 recurrence over the chunk -> s2 spike BALLOTS into S2M
        // (no registers carried across BAR2; same trick as epi3/M3L).
#pragma unroll
        for (int tt = 0; tt < TC; ++tt) {
#pragma unroll
            for (int u = 0; u < 2; ++u) {
#pragma unroll
                for (int r = 0; r < 4; ++r) {
                    int n = nb0 + u * 16 + r;
                    float4 p2 = PL2[n];
                    float cur = ((u == 0) ? D0[tt][r] : D1[tt][r]) + p2.x;
                    float rf = ((m2[u][r] - p2.z) > 0.f) ? 1.f : 0.f;
                    float mm = fmaf(p2.y, m2[u][r], cur);
                    mm = fmaf(-rf, p2.z, mm);
                    m2[u][r] = mm;
                    bool s2 = (mm - p2.z) > 0.f;
                    unsigned long long mk = __ballot(s2);   // bit at lane = (g<<4)|b
                    if (lane == 0) S2M[tt][2 * w + u][r] = mk;
                }
            }
        }
        __syncthreads();   // BAR2: GEMM2 frag reads + pbuf + S2M all complete

        // ---- wave0: m3s recurrence for the previous chunk (tiny: 2 fmaf/t) ----
        if (w == 0 && c > 0 && lane < 32) {
#pragma unroll
            for (int tt = 0; tt < TC; ++tt) {
                float p = pbuf[tt][lane];
                float mm3 = fmaf(bto, m3s, p);
                mm3 = mm3 + bo;
                m3s = mm3;
                float spk = ((m3s - 1.0f) > 0.f) ? 1.f : 0.f;
                float om3 = __shfl_xor(m3s, 16, 64);
                float osp = __shfl_xor(spk, 16, 64);
                if (lane < 16) {
                    *(float4*)(rec + ((size_t)(t0 - TC + tt) * BB + b0 + wb) * 4) =
                        make_float4(spk, osp, m3s, om3);
                }
            }
        }

        // rebuild s2 B-frags from S2M: thread's bit = (mask >> lane) & 1.
        // Wave-uniform mask addresses -> LDS broadcast reads, no conflicts.
#pragma unroll
        for (int tt = 0; tt < TC; ++tt) {
            unsigned sp[2][4];
#pragma unroll
            for (int u = 0; u < 2; ++u)
#pragma unroll
            for (int r = 0; r < 4; ++r) {
                unsigned long long mk = S2M[tt][2 * w + u][r];
                sp[u][r] = ((mk >> lane) & 1ull) ? 0x3F80u : 0u;
            }
            *(uint2*)(&frag[tt][sb0])       = make_uint2(sp[0][0] | (sp[0][1] << 16), sp[0][2] | (sp[0][3] << 16));
            *(uint2*)(&frag[tt][sb0 + 256]) = make_uint2(sp[1][0] | (sp[1][1] << 16), sp[1][2] | (sp[1][3] << 16));
        }
        __syncthreads();   // BAR3: s2 frags visible

        // ---- GEMM3: one weight pass (layer 3) feeds all TC timesteps ----
#pragma unroll
        for (int tt = 0; tt < TC; ++tt) {
            D0[tt] = (f32x4_t){0.f, 0.f, 0.f, 0.f};
            D1[tt] = (f32x4_t){0.f, 0.f, 0.f, 0.f};
        }
        GPHASE(W3, W2);            // steps 6,7 preload NEXT chunk's layer-2 kt0,kt1

        // epi3: LIF3 recurrence over the chunk -> s3 ballots -> M3L
#pragma unroll
        for (int tt = 0; tt < TC; ++tt) {
#pragma unroll
            for (int u = 0; u < 2; ++u) {
#pragma unroll
                for (int r = 0; r < 4; ++r) {
                    int n = nb0 + u * 16 + r;
                    float4 p3 = PL3[n];
                    float cur = ((u == 0) ? D0[tt][r] : D1[tt][r]) + p3.x;
                    float rf = ((m4[u][r] - p3.z) > 0.f) ? 1.f : 0.f;
                    float mm = fmaf(p3.y, m4[u][r], cur);
                    mm = fmaf(-rf, p3.z, mm);
                    m4[u][r] = mm;
                    bool s3 = (mm - p3.z) > 0.f;
                    unsigned long long mk = __ballot(s3);   // bit at lane = (g<<4)|b
                    if (lane == 0) M3L[tt][2 * w + u][r] = mk;
                }
            }
        }
        __syncthreads();   // BAR4: M3L visible; frag free for next phase A
    }

    // final chunk's li_out: serial walker (end of kernel, cost negligible)
    if (w == 0) {
#pragma unroll
        for (int tt = 0; tt < TC; ++tt)
            li_walker_bits(WoutS, M3L[tt], wb, ooc, bto, bo, m3s,
                           rec, TT - TC + tt, b0, lane);
    }
}

// out[r,o] = (ascending-k fma dot) + b_pred[o]
__global__ __launch_bounds__(256) void pred_kernel(
    const float* __restrict__ rec, const float* __restrict__ W_pred,
    const float* __restrict__ b_pred, float* __restrict__ out)
{
#pragma clang fp contract(off)
    int r = blockIdx.x * 256 + threadIdx.x;   // 0..4095
    const float* f = rec + (size_t)r * 256;
    float a0 = 0.f, a1 = 0.f;
#pragma unroll 4
    for (int c = 0; c < 256; ++c) {
        float v = f[c];
        a0 = fmaf(v, W_pred[c], a0);
        a1 = fmaf(v, W_pred[256 + c], a1);
    }
    out[r * 2 + 0] = a0 + b_pred[0];
    out[r * 2 + 1] = a1 + b_pred[1];
}

extern "C" void kernel_launch(void* const* d_in, const int* in_sizes, int n_in,
                              void* d_out, int out_size, void* d_ws, size_t ws_size,
                              hipStream_t stream)
{
    const float* x        = (const float*)d_in[0];
    const float* W_in     = (const float*)d_in[1];
    const float* b_in     = (const float*)d_in[2];
    const float* beta_in  = (const float*)d_in[3];
    const float* thr_in   = (const float*)d_in[4];
    const float* W_h      = (const float*)d_in[5];
    const float* b_h      = (const float*)d_in[6];
    const float* beta_h   = (const float*)d_in[7];
    const float* thr_h    = (const float*)d_in[8];
    const float* W_h2     = (const float*)d_in[9];
    const float* b_h2     = (const float*)d_in[10];
    const float* beta_h2  = (const float*)d_in[11];
    const float* thr_h2   = (const float*)d_in[12];
    const float* W_out    = (const float*)d_in[13];
    const float* b_out    = (const float*)d_in[14];
    const float* beta_out = (const float*)d_in[15];
    const float* W_pred   = (const float*)d_in[16];
    const float* b_pred   = (const float*)d_in[17];

    char* ws = (char*)d_ws;
    unsigned short* WA = (unsigned short*)(ws + WS_WA_B);
    float* emb = (float*)(ws + WS_EMB_B);
    float* rec = (float*)(ws + WS_REC_B);

    split_weights_kernel<<<1536, 256, 0, stream>>>(W_h, W_h2, WA);
    setup_emb_kernel<<<1, 64, 0, stream>>>(emb);

    snn_main_kernel<<<NBLK, 512, 0, stream>>>(
        x, W_in, b_in, beta_in, thr_in,
        b_h, beta_h, thr_h,
        b_h2, beta_h2, thr_h2,
        W_out, b_out, beta_out,
        WA, emb, rec);

    pred_kernel<<<BB / 256, 256, 0, stream>>>(rec, W_pred, b_pred, (float*)d_out);
}

// Round 18
// 652.126 us; speedup vs baseline: 1.0237x; 1.0237x over previous
//
#include <hip/hip_runtime.h>
#include <hip/hip_bf16.h>

#define TT 64
#define BB 4096
#define HH 256
#define BMb 16             // batches per block
#define NBLK (BB / BMb)    // 256 blocks -> 1 block/CU, 8 waves (2/SIMD)
#define TC 4               // timesteps per weight pass (chunk)
#define NCH (TT / TC)      // 16 chunks

typedef short bf16x8_t __attribute__((ext_vector_type(8)));
typedef float f32x4_t  __attribute__((ext_vector_type(4)));

// d_ws layout (byte offsets)
#define WS_WA_B   0u          // split bf16 weights, wave-contiguous layout: 768 KB
#define WS_EMB_B  786432u     // emb f32
#define WS_REC_B  1048576u    // rec f32 [T][B][4], 4 MB

__device__ __forceinline__ float clip01f(float v) {
    return fminf(fmaxf(v, 0.0f), 1.0f);
}

__global__ __launch_bounds__(64) void setup_emb_kernel(float* __restrict__ emb) {
    int i = threadIdx.x;
    const double sigma = 64.0 / 10.0;
    const double c = 32.0;
    double d = ((double)i - c) / sigma;
    double e = exp(-0.5 * (d * d));
    double d0 = (0.0 - c) / sigma;
    double emin = exp(-0.5 * (d0 * d0));
    emb[i] = (float)((e - emin) / (1.0 - emin));
}

// Exact 3-way split w = hi + mid + lo into bf16 parts (residuals exact).
// WAVE-CONTIGUOUS layout (R18): one wave's (layer,kt) group is a single 6KB
// run so ISSUE6 needs ONE base + immediate offsets (12 address VGPRs -> ~4).
// flat = ((((wave*2+layer)*8+kt)*3+part)*2+tile)*512 + lane*8 + j   (shorts)
// Chunk order within a kt-group = (part*2+tile)*1024B — IDENTICAL to the ring
// slot layout, so the same bytes land in the same LDS positions as before ->
// downstream bit-identical. Fragment mapping per tile unchanged:
// A[m=lane&15][k=(lane>>4)*8+j], ntile = wave*2 + tile.
__global__ __launch_bounds__(256) void split_weights_kernel(
    const float* __restrict__ W_h, const float* __restrict__ W_h2,
    unsigned short* __restrict__ WA)
{
    int flat = blockIdx.x * 256 + threadIdx.x;     // < 393216
    int j     = flat & 7;
    int lane  = (flat >> 3) & 63;
    int c     = flat >> 9;         // 512-short chunk index
    int tile  = c & 1;
    int c2    = c >> 1;
    int part  = c2 % 3;
    int c3    = c2 / 3;
    int kt    = c3 & 7;
    int c4    = c3 >> 3;
    int layer = c4 & 1;
    int wv    = c4 >> 1;           // wave 0..7
    int ntile = wv * 2 + tile;
    int k = kt * 32 + (lane >> 4) * 8 + j;
    int n = ntile * 16 + (lane & 15);
    const float* W = layer ? W_h2 : W_h;           // row-major [n][k] = W[n*256+k]
    float w = W[n * HH + k];
    __hip_bfloat16 h = __float2bfloat16(w);
    float r1 = w - __bfloat162float(h);
    __hip_bfloat16 m = __float2bfloat16(r1);
    float r2 = r1 - __bfloat162float(m);
    __hip_bfloat16 l = __float2bfloat16(r2);
    __hip_bfloat16 v = (part == 0) ? h : ((part == 1) ? m : l);
    WA[flat] = *reinterpret_cast<unsigned short*>(&v);
}

union U16x8 { uint4 u; bf16x8_t v; };

// ---- TC=4 @ 512thr, R16 base (session best 582us) + contiguous-weight ISSUE.
// R17 falsified the held-register theory (s2w removal changed nothing). The
// remaining spill suspect is TRANSIENT pressure: 6 scattered 64-bit global
// addresses per ISSUE6 (12 VGPRs + add chains) co-live with D(32) + hoisted
// fragments. Contiguous layout -> 1 base + imm offsets (compiler folds
// 0..3072 into the 13-bit inst offset, one extra base for 4096/5120), and the
// per-wave weight stream becomes sequential in memory (L2-friendly).
// Per-D accumulation order unchanged (kt asc, parts 0,1,2, one MFMA per part
// per kt) -> bit-identical output (canary absmax 0.002365112).

#define AS1 __attribute__((address_space(1)))
#define AS3 __attribute__((address_space(3)))
__device__ __forceinline__ void gl16(const void* g, void* l) {
    __builtin_amdgcn_global_load_lds((AS1 const void*)g, (AS3 void*)l, 16, 0, 0);
}

// Issue the 6 loads of kt-group ktn of weight base Wc (wave-contiguous: kt
// stride 6144B) into ring slot sl. Wc pre-offset by wave*6144u4 + lane.
// Chunk order (part*2+tile)*1024B matches the ring slot layout exactly.
#define ISSUE6(Wc, ktn, sl) do {                                               \
    const char* gb_ = (const char*)(Wc) + (ktn) * 6144;                        \
    char* lb_ = myring + (sl) * 6144;                                          \
    gl16(gb_,          lb_);                                                   \
    gl16(gb_ + 1024,   lb_ + 1024);                                            \
    gl16(gb_ + 2048,   lb_ + 2048);                                            \
    gl16(gb_ + 3072,   lb_ + 3072);                                            \
    gl16(gb_ + 4096,   lb_ + 4096);                                            \
    gl16(gb_ + 5120,   lb_ + 5120);                                            \
} while (0)

// 8 MFMAs of one weight part: per tt, read its B-frag locally, 2 MFMAs, release.
#define MFMA8T(wa_, wb_, ktb) do {                                             \
    _Pragma("unroll")                                                          \
    for (int tt_ = 0; tt_ < TC; ++tt_) {                                       \
        U16x8 br_; br_.u = BfL[tt_ * 512 + (ktb) * 64];                        \
        D0[tt_] = __builtin_amdgcn_mfma_f32_16x16x32_bf16(wa_.v, br_.v, D0[tt_], 0, 0, 0); \
        D1[tt_] = __builtin_amdgcn_mfma_f32_16x16x32_bf16(wb_.v, br_.v, D1[tt_], 0, 0, 0); \
    }                                                                          \
} while (0)

// One kt step: head vmcnt(6) [kt landed; newer 6 in flight]; 3 part-blocks
// with NO asm except part-2's lgkmcnt(0)+SB right before ISSUE6 (WAR proof).
#define STEPT(sl, ktb, Wi, kti) do {                                           \
    asm volatile("s_waitcnt vmcnt(6)" ::: "memory");                           \
    __builtin_amdgcn_sched_barrier(0);                                         \
    {                                                                          \
        U16x8 wa_, wb_;                                                        \
        wa_.u = ringRd[(sl) * 384 + 0];                                        \
        wb_.u = ringRd[(sl) * 384 + 64];                                       \
        MFMA8T(wa_, wb_, ktb);                                                 \
    }                                                                          \
    {                                                                          \
        U16x8 wa_, wb_;                                                        \
        wa_.u = ringRd[(sl) * 384 + 128];                                      \
        wb_.u = ringRd[(sl) * 384 + 192];                                      \
        MFMA8T(wa_, wb_, ktb);                                                 \
    }                                                                          \
    {                                                                          \
        U16x8 wa_, wb_;                                                        \
        wa_.u = ringRd[(sl) * 384 + 256];                                      \
        wb_.u = ringRd[(sl) * 384 + 320];                                      \
        asm volatile("s_waitcnt lgkmcnt(0)" ::: "memory");                     \
        __builtin_amdgcn_sched_barrier(0);                                     \
        ISSUE6(Wi, kti, sl);                                                   \
        MFMA8T(wa_, wb_, ktb);                                                 \
    }                                                                          \
} while (0)

// kt = 0..7 ascending; entry: slot0=kt0, slot1=kt1 landed (barrier vmcnt drain).
// Steps 0..5 refill kt+2; steps 6,7 preload the NEXT pass's kt0,kt1 (Wn).
#define GPHASE(Wc, Wn) do {                                                    \
    STEPT(0, 0, Wc, 2);                                                        \
    STEPT(1, 1, Wc, 3);                                                        \
    STEPT(0, 2, Wc, 4);                                                        \
    STEPT(1, 3, Wc, 5);                                                        \
    STEPT(0, 4, Wc, 6);                                                        \
    STEPT(1, 5, Wc, 7);                                                        \
    STEPT(0, 6, Wn, 0);                                                        \
    STEPT(1, 7, Wn, 1);                                                        \
} while (0)

// p-dot for one timestep (no recurrence -> parallel across waves). Ascending-k
// chain p = p + (bit ? wv : 0), identical text/order to the verified walker ->
// bit-identical p. One lane computes one (batch, channel) pair.
__device__ __forceinline__ void compute_p(
    const float* __restrict__ WoutS, const unsigned long long (*__restrict__ M3Lt)[4],
    int wb, int ooc, float* __restrict__ pout, int lane)
{
    if (lane < 32) {
        float p = 0.f;
        for (int k = 0; k < HH; ++k) {
            int ww = k >> 4, gg = (k >> 2) & 3, reg = k & 3;
            unsigned long long word = M3Lt[ww][reg];
            unsigned w32 = (gg < 2) ? (unsigned)word : (unsigned)(word >> 32);
            int sh = ((gg & 1) << 4) | wb;
            unsigned bit = (w32 >> sh) & 1u;
            float wv = WoutS[ooc * HH + k];
            p = p + (bit ? wv : 0.f);           // skip-zero == exact chain
        }
        pout[lane] = p;
    }
}

// Full serial walker — used only for the final chunk. Identical chains.
__device__ __forceinline__ void li_walker_bits(
    const float* __restrict__ WoutS, const unsigned long long (*__restrict__ M3Lt)[4],
    int wb, int ooc, float bto, float bo, float& m3s,
    float* __restrict__ rec, int t, int b0, int lane)
{
    if (lane < 32) {
        float p = 0.f;
        for (int k = 0; k < HH; ++k) {
            int ww = k >> 4, gg = (k >> 2) & 3, reg = k & 3;
            unsigned long long word = M3Lt[ww][reg];
            unsigned w32 = (gg < 2) ? (unsigned)word : (unsigned)(word >> 32);
            int sh = ((gg & 1) << 4) | wb;
            unsigned bit = (w32 >> sh) & 1u;
            float wv = WoutS[ooc * HH + k];
            p = p + (bit ? wv : 0.f);
        }
        float mm3 = fmaf(bto, m3s, p);
        mm3 = mm3 + bo;
        m3s = mm3;
        float spk = ((m3s - 1.0f) > 0.f) ? 1.f : 0.f;
        float om3 = __shfl_xor(m3s, 16, 64);
        float osp = __shfl_xor(spk, 16, 64);
        if (lane < 16) {
            *(float4*)(rec + ((size_t)t * BB + b0 + wb) * 4) =
                make_float4(spk, osp, m3s, om3);
        }
    }
}

__global__ __launch_bounds__(512) void snn_main_kernel(
    const float* __restrict__ x,
    const float* __restrict__ W_in, const float* __restrict__ b_in,
    const float* __restrict__ beta_in, const float* __restrict__ thr_in,
    const float* __restrict__ b_h, const float* __restrict__ beta_h, const float* __restrict__ thr_h,
    const float* __restrict__ b_h2, const float* __restrict__ beta_h2, const float* __restrict__ thr_h2,
    const float* __restrict__ W_out, const float* __restrict__ b_out, const float* __restrict__ beta_out,
    const unsigned short* __restrict__ WA, const float* __restrict__ emb,
    float* __restrict__ rec)
{
#pragma clang fp contract(off)   // all contraction EXPLICIT via fmaf
    const int tid = threadIdx.x;
    const int w = tid >> 6;       // wave 0..7: owns n-tiles 2w, 2w+1
    const int lane = tid & 63;
    const int b = lane & 15;      // batch column (D col = lane&15)
    const int g = lane >> 4;      // row group   (D row = g*4+reg)
    const int b0 = blockIdx.x * BMb;

    // B-frag buffer: s1 for GEMM2, rewritten with s2 (from s2w regs) after
    // BAR2 for GEMM3. 32 KB.
    __shared__ __align__(16) unsigned short frag[TC][8 * 64 * 8];
    __shared__ unsigned long long M3L[TC][16][4];           // s3 ballots (2 KB)
    __shared__ float pbuf[TC][32];                          // li_out dots (512 B)
    __shared__ __align__(16) float WoutS[2 * HH];
    __shared__ float4 PL1a[HH];   // {wi0, wi1, wi2, b_in}
    __shared__ float2 PL1b[HH];   // {bt1c, th1}
    __shared__ float4 PL2[HH];    // {b_h,  bt2c, th2, -}
    __shared__ float4 PL3[HH];    // {b_h2, bt3c, th3, -}
    __shared__ float  xs[TT][BMb][3];   // staged x slice (12 KB)
    __shared__ float  embS[TT];
    // Wave-local weight ring: 8 waves x 2 slots x 6KB = 96 KB. Total ~159 KB.
    __shared__ __align__(16) char ring[8 * 2 * 6144];

    char* myring = ring + w * 12288;                        // wave-uniform dest base
    const uint4* ringRd = (const uint4*)(ring + w * 12288 + lane * 16);
    const uint4* BfL = (const uint4*)frag + lane;           // B-frag read base

    WoutS[tid] = W_out[tid];      // 512 threads = 512 elems
    if (tid < HH) {
        int n = tid;
        PL1a[n] = make_float4(W_in[n * 3], W_in[n * 3 + 1], W_in[n * 3 + 2], b_in[n]);
        PL1b[n] = make_float2(clip01f(beta_in[n]), thr_in[n]);
        PL2[n]  = make_float4(b_h[n],  clip01f(beta_h[n]),  thr_h[n],  0.f);
        PL3[n]  = make_float4(b_h2[n], clip01f(beta_h2[n]), thr_h2[n], 0.f);
    }
    if (tid < TT) embS[tid] = emb[tid];
#pragma unroll
    for (int i = tid; i < TT * BMb; i += 512) {   // 2 iters: 64 t * 16 batches
        int ts = i >> 4, bb = i & 15;
        const float* xp = x + ((size_t)ts * BB + b0 + bb) * 3;
        xs[ts][bb][0] = xp[0];
        xs[ts][bb][1] = xp[1];
        xs[ts][bb][2] = xp[2];
    }

    // this thread's 8 neurons: n = (2w+u)*16 + g*4 + r, u in {0,1}
    const int nb0 = w * 32 + g * 4;

    float m1[2][4], m2[2][4], m4[2][4];
#pragma unroll
    for (int u = 0; u < 2; ++u)
#pragma unroll
        for (int r = 0; r < 4; ++r) { m1[u][r] = 0.f; m2[u][r] = 0.f; m4[u][r] = 0.f; }

    // spike -> B-frag LDS address for tile nt=2w+u (one b64 per thread per tile):
    // k=n: kt2 = nt>>1 = w, q = (nt&1)*2 + (g>>1), dst_lane = q*16+b, j0 = (g&1)*4
    const int sb0 = ((w * 64 + ((g >> 1) * 16 + b)) * 8 + (g & 1) * 4);

    // li_out walker state (lanes 0..31): wb = batch, ooc = channel
    const int wb = lane & 15;
    const int ooc = (lane >> 4) & 1;
    float bto = clip01f(beta_out[ooc]);
    float bo = b_out[ooc];
    float m3s = 0.f;

    // A-fragment bases, wave-contiguous layout (uint4 units): wave stride
    // 6144 u4 (96 KB), layer stride 3072 u4 (48 KB), kt stride 384 u4 (6 KB).
    const uint4* W2 = (const uint4*)WA + (size_t)w * 6144 + lane;   // layer2
    const uint4* W3 = W2 + 3072;                                    // layer3

    ISSUE6(W2, 0, 0);             // chunk-0 layer-2 kt0 in flight before the loop
    ISSUE6(W2, 1, 1);             // chunk-0 layer-2 kt1 (depth-2 invariant)

    __syncthreads();              // LDS init visible; also drains the preloads

#pragma unroll 1
    for (int c = 0; c < NCH; ++c) {
        const int t0 = c * TC;

        // ---- phase A: layer 1 for TC timesteps (m1 recurrence sequential);
        //      spikes -> s1 B-frags for the whole chunk ----
#pragma unroll
        for (int tt = 0; tt < TC; ++tt) {
            const int t = t0 + tt;
            float et = embS[t];
            float xe0 = xs[t][b][0] * et;
            float xe1 = xs[t][b][1] * et;
            float xe2 = xs[t][b][2] * et;
            unsigned sp[2][4];
#pragma unroll
            for (int u = 0; u < 2; ++u)
#pragma unroll
            for (int r = 0; r < 4; ++r) {
                int n = nb0 + u * 16 + r;
                float4 pa = PL1a[n];
                float2 pb = PL1b[n];
                float a1 = xe0 * pa.x;
                a1 = fmaf(xe1, pa.y, a1);
                a1 = fmaf(xe2, pa.z, a1);
                float cur = a1 + pa.w;
                float rf = ((m1[u][r] - pb.y) > 0.f) ? 1.f : 0.f;  // reset from PREVIOUS mem
                float mm = fmaf(pb.x, m1[u][r], cur);              // contracted: beta*m + cur
                mm = fmaf(-rf, pb.y, mm);                          // contracted: - reset*thr
                m1[u][r] = mm;
                sp[u][r] = ((mm - pb.y) > 0.f) ? 0x3F80u : 0u;     // bf16 1.0 / 0.0
            }
            *(uint2*)(&frag[tt][sb0])       = make_uint2(sp[0][0] | (sp[0][1] << 16), sp[0][2] | (sp[0][3] << 16));
            *(uint2*)(&frag[tt][sb0 + 256]) = make_uint2(sp[1][0] | (sp[1][1] << 16), sp[1][2] | (sp[1][3] << 16));
        }
        __syncthreads();   // BAR1: s1 frags visible; ring kt0,kt1 landed

        // ---- waves 0..3: previous chunk's li_out dots (wave w -> tt=w),
        //      hidden under GEMM2. M3L(prev) rewritten only in epi3. ----
        if (w < TC && c > 0)
            compute_p(WoutS, M3L[w], wb, ooc, pbuf[w], lane);

        // ---- GEMM2: one weight pass (layer 2) feeds all TC timesteps ----
        f32x4_t D0[TC], D1[TC];
#pragma unroll
        for (int tt = 0; tt < TC; ++tt) {
            D0[tt] = (f32x4_t){0.f, 0.f, 0.f, 0.f};
            D1[tt] = (f32x4_t){0.f, 0.f, 0.f, 0.f};
        }
        GPHASE(W2, W3);            // steps 6,7 preload layer-3 kt0,kt1

        // epi2: LIF2 recurrence over the chunk (sequential tt) -> s2 words in regs
        uint2 s2w[TC][2];
#pragma unroll
        for (int tt = 0; tt < TC; ++tt) {
            unsigned sp[2][4];
#pragma unroll
            for (int r = 0; r < 4; ++r) {
                int n0 = nb0 + r;
                float4 p2 = PL2[n0];
                float cur = D0[tt][r] + p2.x;
                float rf = ((m2[0][r] - p2.z) > 0.f) ? 1.f : 0.f;
                float mm = fmaf(p2.y, m2[0][r], cur);
                mm = fmaf(-rf, p2.z, mm);
                m2[0][r] = mm;
                sp[0][r] = ((mm - p2.z) > 0.f) ? 0x3F80u : 0u;
            }
#pragma unroll
            for (int r = 0; r < 4; ++r) {
                int n1 = nb0 + 16 + r;
                float4 p2 = PL2[n1];
                float cur = D1[tt][r] + p2.x;
                float rf = ((m2[1][r] - p2.z) > 0.f) ? 1.f : 0.f;
                float mm = fmaf(p2.y, m2[1][r], cur);
                mm = fmaf(-rf, p2.z, mm);
                m2[1][r] = mm;
                sp[1][r] = ((mm - p2.z) > 0.f) ? 0x3F80u : 0u;
            }
            s2w[tt][0] = make_uint2(sp[0][0] | (sp[0][1] << 16), sp[0][2] | (sp[0][3] << 16));
            s2w[tt][1] = make_uint2(sp[1][0] | (sp[1][1] << 16), sp[1][2] | (sp[1][3] << 16));
        }
        __syncthreads();   // BAR2: all GEMM2 frag reads + pbuf writes complete

        // ---- wave0: m3s recurrence for the previous chunk (tiny: 2 fmaf/t) ----
        if (w == 0 && c > 0 && lane < 32) {
#pragma unroll
            for (int tt = 0; tt < TC; ++tt) {
                float p = pbuf[tt][lane];
                float mm3 = fmaf(bto, m3s, p);
                mm3 = mm3 + bo;
                m3s = mm3;
                float spk = ((m3s - 1.0f) > 0.f) ? 1.f : 0.f;
                float om3 = __shfl_xor(m3s, 16, 64);
                float osp = __shfl_xor(spk, 16, 64);
                if (lane < 16) {
                    *(float4*)(rec + ((size_t)(t0 - TC + tt) * BB + b0 + wb) * 4) =
                        make_float4(spk, osp, m3s, om3);
                }
            }
        }

#pragma unroll
        for (int tt = 0; tt < TC; ++tt) {
            *(uint2*)(&frag[tt][sb0])       = s2w[tt][0];
            *(uint2*)(&frag[tt][sb0 + 256]) = s2w[tt][1];
        }
        __syncthreads();   // BAR3: s2 frags visible

        // ---- GEMM3: one weight pass (layer 3) feeds all TC timesteps ----
#pragma unroll
        for (int tt = 0; tt < TC; ++tt) {
            D0[tt] = (f32x4_t){0.f, 0.f, 0.f, 0.f};
            D1[tt] = (f32x4_t){0.f, 0.f, 0.f, 0.f};
        }
        GPHASE(W3, W2);            // steps 6,7 preload NEXT chunk's layer-2 kt0,kt1

        // epi3: LIF3 recurrence over the chunk -> s3 ballots -> M3L
#pragma unroll
        for (int tt = 0; tt < TC; ++tt) {
#pragma unroll
            for (int u = 0; u < 2; ++u) {
#pragma unroll
                for (int r = 0; r < 4; ++r) {
                    int n = nb0 + u * 16 + r;
                    float4 p3 = PL3[n];
                    float cur = ((u == 0) ? D0[tt][r] : D1[tt][r]) + p3.x;
                    float rf = ((m4[u][r] - p3.z) > 0.f) ? 1.f : 0.f;
                    float mm = fmaf(p3.y, m4[u][r], cur);
                    mm = fmaf(-rf, p3.z, mm);
                    m4[u][r] = mm;
                    bool s3 = (mm - p3.z) > 0.f;
                    unsigned long long mk = __ballot(s3);   // bit at lane = (g<<4)|b
                    if (lane == 0) M3L[tt][2 * w + u][r] = mk;
                }
            }
        }
        __syncthreads();   // BAR4: M3L visible; frag free for next phase A
    }

    // final chunk's li_out: serial walker (end of kernel, cost negligible)
    if (w == 0) {
#pragma unroll
        for (int tt = 0; tt < TC; ++tt)
            li_walker_bits(WoutS, M3L[tt], wb, ooc, bto, bo, m3s,
                           rec, TT - TC + tt, b0, lane);
    }
}

// out[r,o] = (ascending-k fma dot) + b_pred[o]
__global__ __launch_bounds__(256) void pred_kernel(
    const float* __restrict__ rec, const float* __restrict__ W_pred,
    const float* __restrict__ b_pred, float* __restrict__ out)
{
#pragma clang fp contract(off)
    int r = blockIdx.x * 256 + threadIdx.x;   // 0..4095
    const float* f = rec + (size_t)r * 256;
    float a0 = 0.f, a1 = 0.f;
#pragma unroll 4
    for (int c = 0; c < 256; ++c) {
        float v = f[c];
        a0 = fmaf(v, W_pred[c], a0);
        a1 = fmaf(v, W_pred[256 + c], a1);
    }
    out[r * 2 + 0] = a0 + b_pred[0];
    out[r * 2 + 1] = a1 + b_pred[1];
}

extern "C" void kernel_launch(void* const* d_in, const int* in_sizes, int n_in,
                              void* d_out, int out_size, void* d_ws, size_t ws_size,
                              hipStream_t stream)
{
    const float* x        = (const float*)d_in[0];
    const float* W_in     = (const float*)d_in[1];
    const float* b_in     = (const float*)d_in[2];
    const float* beta_in  = (const float*)d_in[3];
    const float* thr_in   = (const float*)d_in[4];
    const float* W_h      = (const float*)d_in[5];
    const float* b_h      = (const float*)d_in[6];
    const float* beta_h   = (const float*)d_in[7];
    const float* thr_h    = (const float*)d_in[8];
    const float* W_h2     = (const float*)d_in[9];
    const float* b_h2     = (const float*)d_in[10];
    const float* beta_h2  = (const float*)d_in[11];
    const float* thr_h2   = (const float*)d_in[12];
    const float* W_out    = (const float*)d_in[13];
    const float* b_out    = (const float*)d_in[14];
    const float* beta_out = (const float*)d_in[15];
    const float* W_pred   = (const float*)d_in[16];
    const float* b_pred   = (const float*)d_in[17];

    char* ws = (char*)d_ws;
    unsigned short* WA = (unsigned short*)(ws + WS_WA_B);
    float* emb = (float*)(ws + WS_EMB_B);
    float* rec = (float*)(ws + WS_REC_B);

    split_weights_kernel<<<1536, 256, 0, stream>>>(W_h, W_h2, WA);
    setup_emb_kernel<<<1, 64, 0, stream>>>(emb);

    snn_main_kernel<<<NBLK, 512, 0, stream>>>(
        x, W_in, b_in, beta_in, thr_in,
        b_h, beta_h, thr_h,
        b_h2, beta_h2, thr_h2,
        W_out, b_out, beta_out,
        WA, emb, rec);

    pred_kernel<<<BB / 256, 256, 0, stream>>>(rec, W_pred, b_pred, (float*)d_out);
}